// Round 4
// baseline (156.647 us; speedup 1.0000x reference)
//
#include <hip/hip_runtime.h>
#include <hip/hip_bf16.h>

#define B_ROWS 4096
#define NROWS  8192   // 2B
#define D      256
#define TILES  64     // NROWS / 128
#define NPAIRS 2080   // TILES*(TILES+1)/2 upper-triangular tile pairs

typedef __attribute__((ext_vector_type(8))) short bf16x8;
typedef __attribute__((ext_vector_type(4))) float floatx4;

// ---------------------------------------------------------------------------
// Kernel 1: fused normalize + pos + selfdot + zero-init of rowsum/out/counter.
// One wave per pair (r, r+B). pos/selfdot from bf16-ROUNDED z (matches GEMM).
// ---------------------------------------------------------------------------
__global__ __launch_bounds__(256) void norm_pos_kernel(
    const float* __restrict__ xi, const float* __restrict__ xj,
    short* __restrict__ z, float* __restrict__ pos,
    float* __restrict__ selfdot, float* __restrict__ rowsum,
    float* __restrict__ out, unsigned int* __restrict__ counter) {
    int gt = blockIdx.x * 256 + threadIdx.x;
    if (gt < NROWS) rowsum[gt] = 0.f;   // visible to sim kernel (kernel boundary)
    if (gt == 0) { out[0] = 0.f; counter[0] = 0u; }

    int p    = blockIdx.x * 4 + (threadIdx.x >> 6);
    int lane = threadIdx.x & 63;
    float4 v1 = ((const float4*)(xi + (size_t)p * D))[lane];
    float4 v2 = ((const float4*)(xj + (size_t)p * D))[lane];
    float ss1 = v1.x * v1.x + v1.y * v1.y + v1.z * v1.z + v1.w * v1.w;
    float ss2 = v2.x * v2.x + v2.y * v2.y + v2.z * v2.z + v2.w * v2.w;
#pragma unroll
    for (int off = 32; off > 0; off >>= 1) {
        ss1 += __shfl_xor(ss1, off);
        ss2 += __shfl_xor(ss2, off);
    }
    float sc1 = 1.0f / fmaxf(sqrtf(ss1), 1e-12f);
    float sc2 = 1.0f / fmaxf(sqrtf(ss2), 1e-12f);

    union { __hip_bfloat16 h[4]; short4 s4; } u1, u2;
    u1.h[0] = __float2bfloat16(v1.x * sc1); u1.h[1] = __float2bfloat16(v1.y * sc1);
    u1.h[2] = __float2bfloat16(v1.z * sc1); u1.h[3] = __float2bfloat16(v1.w * sc1);
    u2.h[0] = __float2bfloat16(v2.x * sc2); u2.h[1] = __float2bfloat16(v2.y * sc2);
    u2.h[2] = __float2bfloat16(v2.z * sc2); u2.h[3] = __float2bfloat16(v2.w * sc2);
    ((short4*)(z + (size_t)p * D))[lane]            = u1.s4;
    ((short4*)(z + (size_t)(p + B_ROWS) * D))[lane] = u2.s4;

    float sd1 = 0.f, sd2 = 0.f, dp = 0.f;
#pragma unroll
    for (int j = 0; j < 4; j++) {
        float a = __bfloat162float(u1.h[j]);
        float b = __bfloat162float(u2.h[j]);
        sd1 += a * a; sd2 += b * b; dp += a * b;
    }
#pragma unroll
    for (int off = 32; off > 0; off >>= 1) {
        sd1 += __shfl_xor(sd1, off);
        sd2 += __shfl_xor(sd2, off);
        dp  += __shfl_xor(dp,  off);
    }
    if (lane == 0) {
        pos[p] = dp; pos[p + B_ROWS] = dp;
        selfdot[p] = sd1; selfdot[p + B_ROWS] = sd2;
    }
}

// ---------------------------------------------------------------------------
// Kernel 2: symmetric fused sim+exp+rowsum (+ last-block loss).
// BARRIER-FREE streaming K-loop: no LDS staging. Fragments load directly from
// global (z is 4 MiB -> L2-resident on every XCD; each wave frag-load covers
// 16 fully-used 64B lines). 2-deep register software pipeline; compiler
// inserts fine-grained vmcnt waits. Block = 4 waves (2x2), wave tile 64x64
// (4x4 of 16x16x32 bf16 MFMA). Epilogue: exp(2s) row+col partials -> LDS ->
// global atomics; last finished block computes the final loss.
// ---------------------------------------------------------------------------
__global__ __launch_bounds__(256) void sim_rowsum_kernel(
    const short* __restrict__ z, float* __restrict__ rowsum,
    const float* __restrict__ pos, const float* __restrict__ selfdot,
    unsigned int* __restrict__ counter, float* __restrict__ out) {
    __shared__ float rs_lds[128];
    __shared__ float cs_lds[128];
    __shared__ unsigned int done_s;
    __shared__ float sdata[4];

    int tid  = threadIdx.x;
    int lane = tid & 63;
    int w    = tid >> 6;       // wave 0..3
    int lm   = lane & 15;
    int lg   = lane >> 4;

    // decode upper-triangular tile pair (ti <= tj)
    int bid = blockIdx.x;
    int ti  = (int)((129.0 - sqrt(16641.0 - 8.0 * (double)bid)) * 0.5);
    while (ti > 0 && ti * TILES - ti * (ti - 1) / 2 > bid) ti--;
    while ((ti + 1) * TILES - (ti + 1) * ti / 2 <= bid) ti++;
    int tj = ti + (bid - (ti * TILES - ti * (ti - 1) / 2));
    int m0 = ti * 128, n0 = tj * 128;

    int wr = (w & 1) * 64;     // wave row offset in tile
    int wc = (w >> 1) * 64;    // wave col offset in tile

    if (tid < 128) { rs_lds[tid] = 0.f; cs_lds[tid] = 0.f; }

    // per-lane fragment base pointers (k folded into load offset)
    const short* arow[4];
    const short* brow[4];
#pragma unroll
    for (int mi = 0; mi < 4; mi++)
        arow[mi] = z + (size_t)(m0 + wr + mi * 16 + lm) * D + lg * 8;
#pragma unroll
    for (int ni = 0; ni < 4; ni++)
        brow[ni] = z + (size_t)(n0 + wc + ni * 16 + lm) * D + lg * 8;

    floatx4 acc[4][4];
#pragma unroll
    for (int mi = 0; mi < 4; mi++)
#pragma unroll
        for (int ni = 0; ni < 4; ni++) acc[mi][ni] = (floatx4){0.f, 0.f, 0.f, 0.f};

    bf16x8 af[2][4], bf[2][4];
#pragma unroll
    for (int mi = 0; mi < 4; mi++) af[0][mi] = *(const bf16x8*)(arow[mi]);
#pragma unroll
    for (int ni = 0; ni < 4; ni++) bf[0][ni] = *(const bf16x8*)(brow[ni]);

#pragma unroll
    for (int it = 0; it < 8; it++) {
        int cur = it & 1, nxt = cur ^ 1;
        if (it < 7) {
            int k = (it + 1) * 32;
#pragma unroll
            for (int mi = 0; mi < 4; mi++)
                af[nxt][mi] = *(const bf16x8*)(arow[mi] + k);
#pragma unroll
            for (int ni = 0; ni < 4; ni++)
                bf[nxt][ni] = *(const bf16x8*)(brow[ni] + k);
        }
#pragma unroll
        for (int mi = 0; mi < 4; mi++)
#pragma unroll
            for (int ni = 0; ni < 4; ni++)
                acc[mi][ni] = __builtin_amdgcn_mfma_f32_16x16x32_bf16(
                    af[cur][mi], bf[cur][ni], acc[mi][ni], 0, 0, 0);
    }

    // epilogue: e = exp(2*sim); rs = row partials, cs = col partials
    float rs[4][4];
    float cs[4];
#pragma unroll
    for (int mi = 0; mi < 4; mi++)
#pragma unroll
        for (int r = 0; r < 4; r++) rs[mi][r] = 0.f;
#pragma unroll
    for (int ni = 0; ni < 4; ni++) cs[ni] = 0.f;

#pragma unroll
    for (int mi = 0; mi < 4; mi++)
#pragma unroll
        for (int ni = 0; ni < 4; ni++)
#pragma unroll
            for (int r = 0; r < 4; r++) {
                float e = __expf(2.0f * acc[mi][ni][r]);
                rs[mi][r] += e;
                cs[ni]    += e;
            }

    bool offdiag = (ti != tj);
    // row side: reduce across lanes lm=0..15 (16 cols each)
#pragma unroll
    for (int mi = 0; mi < 4; mi++)
#pragma unroll
        for (int r = 0; r < 4; r++) {
            float s = rs[mi][r];
            s += __shfl_xor(s, 1); s += __shfl_xor(s, 2);
            s += __shfl_xor(s, 4); s += __shfl_xor(s, 8);
            if (lm == 0) atomicAdd(&rs_lds[wr + mi * 16 + lg * 4 + r], s);
        }
    // col side: reduce across the 4 row-groups
    if (offdiag) {
#pragma unroll
        for (int ni = 0; ni < 4; ni++) {
            float s = cs[ni];
            s += __shfl_xor(s, 16); s += __shfl_xor(s, 32);
            if (lane < 16) atomicAdd(&cs_lds[wc + ni * 16 + lm], s);
        }
    }
    __syncthreads();
    if (tid < 128) {
        atomicAdd(&rowsum[m0 + tid], rs_lds[tid]);
    } else if (offdiag) {
        atomicAdd(&rowsum[n0 + tid - 128], cs_lds[tid - 128]);
    }

    // ---- last-block-done: compute the final loss ----
    __syncthreads();            // all this block's atomics issued+drained
    if (tid == 0) {
        __threadfence();        // release our rowsum updates
        done_s = atomicAdd(counter, 1u);
    }
    __syncthreads();
    if (done_s == (unsigned int)(NPAIRS - 1)) {
        __threadfence();        // acquire all blocks' rowsum updates
        float acc_l = 0.f;
#pragma unroll 4
        for (int r = tid; r < NROWS; r += 256) {
            float rsv = __hip_atomic_load(&rowsum[r], __ATOMIC_RELAXED,
                                          __HIP_MEMORY_SCOPE_AGENT);
            float denom = rsv - __expf(2.0f * selfdot[r]);
            acc_l += -2.0f * pos[r] + logf(denom);
        }
#pragma unroll
        for (int off = 32; off > 0; off >>= 1) acc_l += __shfl_xor(acc_l, off);
        if (lane == 0) sdata[w] = acc_l;
        __syncthreads();
        if (tid == 0)
            out[0] = (sdata[0] + sdata[1] + sdata[2] + sdata[3]) / (float)NROWS;
    }
}

// ---------------------------------------------------------------------------
extern "C" void kernel_launch(void* const* d_in, const int* in_sizes, int n_in,
                              void* d_out, int out_size, void* d_ws, size_t ws_size,
                              hipStream_t stream) {
    const float* xi = (const float*)d_in[0];
    const float* xj = (const float*)d_in[1];
    float* out      = (float*)d_out;

    char* ws        = (char*)d_ws;
    short* z        = (short*)ws;                             // 4 MiB
    float* rowsum   = (float*)(ws + (size_t)NROWS * D * 2);   // 32 KiB
    float* pos      = rowsum + NROWS;                         // 32 KiB
    float* selfdot  = pos + NROWS;                            // 32 KiB
    unsigned int* counter = (unsigned int*)(selfdot + NROWS);

    norm_pos_kernel<<<B_ROWS / 4, 256, 0, stream>>>(xi, xj, z, pos, selfdot,
                                                    rowsum, out, counter);
    sim_rowsum_kernel<<<NPAIRS, 256, 0, stream>>>(z, rowsum, pos, selfdot,
                                                  counter, out);
}